// Round 15
// baseline (24.514 us; speedup 1.0000x reference)
//
#include <hip/hip_runtime.h>

typedef _Float16 f16x8 __attribute__((ext_vector_type(8)));
typedef _Float16 f16x4 __attribute__((ext_vector_type(4)));
typedef __fp16 fp16x2 __attribute__((ext_vector_type(2)));
typedef float f32x4 __attribute__((ext_vector_type(4)));

#define IMG 512
#define NB 32
#define OUTC 118
#define GX 5
#define GY 16
#define NBLK (GX*GY*NB)    /* 2560 = 8 * 320: bijective XCD swizzle */
#define INSTR 48           /* lds_in slot stride (fp16): 42 real + 6 tail slots */
#define IOFF (128*INSTR)   /* 6144 f16 per image plane */
#define VSTR 136           /* v-buffer row stride (fp16) */
#define VOFF (16*VSTR)     /* 2176 f16 per field */
#define VLEN (5*VOFF + 32) /* 10912 f16: fits inside 2*IOFF = 12288 */

// sigma=1.5, 11-tap normalized Gaussian (validated R1-R14)
#define GW_LIST { 0.0010283804f, 0.0075987583f, 0.0360007700f, 0.1093606900f, \
  0.2130055300f, 0.2660117200f, 0.2130055300f, 0.1093606900f, 0.0360007700f, \
  0.0075987583f, 0.0010283804f }

__global__ __launch_bounds__(256, 4) void ssim_mfma(const float* __restrict__ img1,
                                                    const float* __restrict__ img2,
                                                    float* __restrict__ partials) {
    // [0 .. 2*IOFF): staged input (col-major per column), fp16.
    //                DEAD after V-compute; single V buffer [0 .. VLEN) ALIASED on it.
    //                Staging fully overwrites the region with finite f16 -> no
    //                uninit-NaN hazard (R10 lesson). Tail slots 42..47 carry zero
    //                band weight; interior blocks fill them with real rows,
    //                boundary blocks zero-fill.
    __shared__ _Float16 smem[2*IOFF];   // 24,576 B -> LDS allows 6 blocks/CU
    __shared__ float red[4];

    const int tid  = threadIdx.x;
    const int lane = tid & 63;
    const int lm   = lane & 15;
    const int kg   = lane >> 4;
    const int w    = tid >> 6;

    // ---- bijective XCD swizzle: consecutive work-ids share halos -> same XCD L2 ----
    const int d   = (blockIdx.z * GY + blockIdx.y) * GX + blockIdx.x;
    const int wid = (d & 7) * (NBLK / 8) + (d >> 3);
    const int bx  = wid % GX;
    const int t2  = wid / GX;
    const int by  = t2 % GY;
    const int bz  = t2 / GY;

    const float* __restrict__ p1 = img1 + (size_t)bz * (IMG*IMG);
    const float* __restrict__ p2 = img2 + (size_t)bz * (IMG*IMG);
    const int x0 = bx * OUTC;
    const int y0 = by * 32;

    // ---- per-wave barrier-free staging: wave w owns staged cols [32w, 32w+32) ----
    {
        const int cl    = lane & 31;
        const int half  = lane >> 5;
        const int ci    = w*32 + cl;
        const int slot0 = half * 24;
        union { fp16x2 p2v[12]; f16x8 v[3]; } ua, ub;

        // interior: every row y0-5..y0+42 and col x0-5..x0+122 in-bounds
        const bool interior = (by >= 1) & (by <= 14) & (bx >= 1) & (bx <= 3);
        if (interior) {
            // unconditional linear loads — no cmp/cndmask, strength-reduced addrs
            const size_t base = (size_t)(y0 - 5 + slot0) * IMG + (x0 - 5 + ci);
            const float* ap = p1 + base;
            const float* bp = p2 + base;
#pragma unroll
            for (int pp = 0; pp < 12; ++pp) {
                const float a0 = ap[(size_t)(2*pp)*IMG], a1 = ap[(size_t)(2*pp+1)*IMG];
                const float b0 = bp[(size_t)(2*pp)*IMG], b1 = bp[(size_t)(2*pp+1)*IMG];
                ua.p2v[pp] = __builtin_amdgcn_cvt_pkrtz(a0, a1);
                ub.p2v[pp] = __builtin_amdgcn_cvt_pkrtz(b0, b1);
            }
        } else {
            const int gc = x0 - 5 + ci;
            const bool okc = (gc >= 0) && (gc < IMG);
            const int gcc = okc ? gc : 0;
#pragma unroll
            for (int pp = 0; pp < 12; ++pp) {
                const int s0 = slot0 + 2*pp;
                const int ar0 = y0 - 5 + s0;
                const int ar1 = ar0 + 1;
                const bool ok0 = okc & (s0   < 42) & (ar0 >= 0) & (ar0 < IMG);
                const bool ok1 = okc & (s0+1 < 42) & (ar1 >= 0) & (ar1 < IMG);
                const int i0 = ok0 ? ar0 : 0, i1 = ok1 ? ar1 : 0;
                float a0 = p1[i0*IMG + gcc], a1 = p1[i1*IMG + gcc];
                float b0 = p2[i0*IMG + gcc], b1 = p2[i1*IMG + gcc];
                a0 = ok0 ? a0 : 0.f;  a1 = ok1 ? a1 : 0.f;
                b0 = ok0 ? b0 : 0.f;  b1 = ok1 ? b1 : 0.f;
                ua.p2v[pp] = __builtin_amdgcn_cvt_pkrtz(a0, a1);
                ub.p2v[pp] = __builtin_amdgcn_cvt_pkrtz(b0, b1);
            }
        }
        _Float16* dst = &smem[ci*INSTR + slot0];
#pragma unroll
        for (int m = 0; m < 3; ++m) {
            *(f16x8*)(dst + 8*m)        = ua.v[m];
            *(f16x8*)(dst + IOFF + 8*m) = ub.v[m];
        }
    }

    // ---- banded weight fragment WITHOUT LDS: wu.h[i] = GW[kg*8+i-lm] ----
    union { fp16x2 p[4]; f16x8 v; } wu;
    {
        const float GWc[11] = GW_LIST;
        float gf = 0.f;
#pragma unroll
        for (int k = 0; k < 11; ++k) gf = (lane == k) ? GWc[k] : gf;
        const int gi = __float_as_int(gf);
        float hv[8];
#pragma unroll
        for (int i = 0; i < 8; ++i) {
            const int t = kg*8 + i - lm;
            const int bp = __builtin_amdgcn_ds_bpermute(t * 4, gi);
            hv[i] = ((unsigned)t < 11u) ? __int_as_float(bp) : 0.f;
        }
#pragma unroll
        for (int j = 0; j < 4; ++j)
            wu.p[j] = __builtin_amdgcn_cvt_pkrtz(hv[2*j], hv[2*j+1]);
    }

    const f32x4 zc = {0.f, 0.f, 0.f, 0.f};

    // ---- V-compute, BOTH strips, wave-local (no barrier after staging) ----
    f16x4 pk[2][2][5];
#pragma unroll
    for (int s = 0; s < 2; ++s) {
#pragma unroll
        for (int q = 0; q < 2; ++q) {
            const int cb = 2*w + q;
            const _Float16* colp = &smem[(cb*16 + lm)*INSTR + s*16 + kg*8];
            const f16x8 xf = *(const f16x8*)colp;
            const f16x8 yf = *(const f16x8*)(colp + IOFF);
            const f16x8 fr[5] = { xf, yf, xf*xf, yf*yf, xf*yf };
#pragma unroll
            for (int f = 0; f < 5; ++f) {
                const f32x4 dd = __builtin_amdgcn_mfma_f32_16x16x32_f16(fr[f], wu.v, zc, 0, 0, 0);
                union { fp16x2 p[2]; f16x4 v4; } c;
                c.p[0] = __builtin_amdgcn_cvt_pkrtz(dd[0], dd[1]);
                c.p[1] = __builtin_amdgcn_cvt_pkrtz(dd[2], dd[3]);
                pk[s][q][f] = c.v4;
            }
        }
    }

    __syncthreads();   // barA: ALL input reads done -> aliased buf may be written

    // ---- V0 -> buf (aliased over dead input) ----
    {
        _Float16* b = &smem[lm*VSTR + 2*w*16 + kg*4];
#pragma unroll
        for (int q = 0; q < 2; ++q)
#pragma unroll
            for (int f = 0; f < 5; ++f)
                *(f16x4*)(b + f*VOFF + q*16) = pk[0][q][f];
    }
    __syncthreads();   // barB: buf = strip-0 V

    float local = 0.f;
    // H: A = V rows (b128, k=cols contiguous), B = weights; + SSIM map.
    auto stage_h = [&]() {
#pragma unroll
        for (int q = 0; q < 2; ++q) {
            const int xx = 2*w + q;
            const _Float16* vp = &smem[lm*VSTR + xx*16 + kg*8];
            f32x4 dd[5];
#pragma unroll
            for (int f = 0; f < 5; ++f) {
                const f16x8 a = *(const f16x8*)(vp + f*VOFF);
                dd[f] = __builtin_amdgcn_mfma_f32_16x16x32_f16(a, wu.v, zc, 0, 0, 0);
            }
            const int X = xx*16 + lm;
            const bool valid = (X < OUTC) & (x0 + X < IMG);
            float s4 = 0.f;
#pragma unroll
            for (int j = 0; j < 4; ++j) {
                const float mu1 = dd[0][j], mu2 = dd[1][j];
                const float m11 = mu1*mu1, m22 = mu2*mu2, m12 = mu1*mu2;
                const float s1 = dd[2][j] - m11, s2 = dd[3][j] - m22, sx = dd[4][j] - m12;
                const float num = (2.f*m12 + 1e-4f) * (2.f*sx + 9e-4f);
                const float den = (m11 + m22 + 1e-4f) * (s1 + s2 + 9e-4f);
                s4 += num * __builtin_amdgcn_rcpf(den);
            }
            local += valid ? s4 : 0.f;
        }
    };

    stage_h();         // H0
    __syncthreads();   // barC: H0 done reading buf

    // ---- V1 -> buf ----
    {
        _Float16* b = &smem[lm*VSTR + 2*w*16 + kg*4];
#pragma unroll
        for (int q = 0; q < 2; ++q)
#pragma unroll
            for (int f = 0; f < 5; ++f)
                *(f16x4*)(b + f*VOFF + q*16) = pk[1][q][f];
    }
    __syncthreads();   // barD: buf = strip-1 V

    stage_h();         // H1

    // ---- block reduction ----
#pragma unroll
    for (int off = 32; off > 0; off >>= 1)
        local += __shfl_down(local, off, 64);
    if (lane == 0) red[w] = local;
    __syncthreads();
    if (tid == 0) {
        partials[(size_t)wid] = red[0] + red[1] + red[2] + red[3];
    }
}

__global__ __launch_bounds__(256) void ssim_finalize(const float* __restrict__ partials,
                                                     float* __restrict__ out) {
    __shared__ double red[4];
    double s = 0.0;
    // 2560 partials = 640 float4
    for (int i = threadIdx.x; i < NBLK/4; i += 256) {
        const float4 v = reinterpret_cast<const float4*>(partials)[i];
        s += (double)v.x + (double)v.y + (double)v.z + (double)v.w;
    }
#pragma unroll
    for (int off = 32; off > 0; off >>= 1)
        s += __shfl_down(s, off, 64);
    if ((threadIdx.x & 63) == 0) red[threadIdx.x >> 6] = s;
    __syncthreads();
    if (threadIdx.x == 0) {
        double tot = red[0] + red[1] + red[2] + red[3];
        out[0] = (float)(1.0 - tot / (32.0 * 512.0 * 512.0));
    }
}

extern "C" void kernel_launch(void* const* d_in, const int* in_sizes, int n_in,
                              void* d_out, int out_size, void* d_ws, size_t ws_size,
                              hipStream_t stream) {
    const float* img1 = (const float*)d_in[0];
    const float* img2 = (const float*)d_in[1];
    float* out = (float*)d_out;
    float* partials = (float*)d_ws;

    dim3 grid(GX, GY, NB);   // 5 x 16 x 32 = 2560 blocks
    ssim_mfma<<<grid, 256, 0, stream>>>(img1, img2, partials);
    ssim_finalize<<<1, 256, 0, stream>>>(partials, out);
}

// Round 16
// 24.362 us; speedup vs baseline: 1.0062x; 1.0062x over previous
//
#include <hip/hip_runtime.h>

typedef _Float16 f16x8 __attribute__((ext_vector_type(8)));
typedef _Float16 f16x4 __attribute__((ext_vector_type(4)));
typedef __fp16 fp16x2 __attribute__((ext_vector_type(2)));
typedef float f32x4 __attribute__((ext_vector_type(4)));

#define IMG 512
#define NB 32
#define OUTC 118
#define GX 5
#define GY 16
#define NBLK (GX*GY*NB)    /* 2560 = 8 * 320: bijective XCD swizzle */
#define INSTR 48           /* lds_in slot stride (fp16): 42 real + 6 tail slots */
#define IOFF (128*INSTR)   /* 6144 f16 per image plane */
#define VSTR 136           /* v-buffer row stride (fp16), 16B-aligned rows */
#define VOFF (16*VSTR)     /* 2176 f16 per field */
#define VLEN (5*VOFF + 32) /* 10912 f16: fits inside 2*IOFF = 12288 */

// sigma=1.5, 11-tap normalized Gaussian (validated R1-R15)
#define GW_LIST { 0.0010283804f, 0.0075987583f, 0.0360007700f, 0.1093606900f, \
  0.2130055300f, 0.2660117200f, 0.2130055300f, 0.1093606900f, 0.0360007700f, \
  0.0075987583f, 0.0010283804f }

__global__ __launch_bounds__(256, 5) void ssim_mfma(const float* __restrict__ img1,
                                                    const float* __restrict__ img2,
                                                    float* __restrict__ partials) {
    // [0 .. 2*IOFF): staged input (col-major per column), fp16.
    //                DEAD after V-compute; single V buffer [0 .. VLEN) ALIASED on it.
    //                Staging fully overwrites the region with finite f16 -> no
    //                uninit-NaN hazard (R10 lesson).
    __shared__ _Float16 smem[2*IOFF];   // 24,576 B -> LDS allows 6 blocks/CU
    __shared__ float red[4];

    const int tid  = threadIdx.x;
    const int lane = tid & 63;
    const int lm   = lane & 15;
    const int kg   = lane >> 4;
    const int w    = tid >> 6;

    // ---- bijective XCD swizzle: consecutive work-ids share halos -> same XCD L2 ----
    const int d   = (blockIdx.z * GY + blockIdx.y) * GX + blockIdx.x;
    const int wid = (d & 7) * (NBLK / 8) + (d >> 3);
    const int bx  = wid % GX;
    const int t2  = wid / GX;
    const int by  = t2 % GY;
    const int bz  = t2 / GY;

    const float* __restrict__ p1 = img1 + (size_t)bz * (IMG*IMG);
    const float* __restrict__ p2 = img2 + (size_t)bz * (IMG*IMG);
    const int x0 = bx * OUTC;
    const int y0 = by * 32;

    // ---- banded weight fragment WITHOUT LDS: wu.h[i] = GW[kg*8+i-lm] ----
    // (built FIRST: ds_bpermute chain issues before the global-load burst)
    union { fp16x2 p[4]; f16x8 v; } wu;
    {
        const float GWc[11] = GW_LIST;
        float gf = 0.f;
#pragma unroll
        for (int k = 0; k < 11; ++k) gf = (lane == k) ? GWc[k] : gf;
        const int gi = __float_as_int(gf);
        float hv[8];
#pragma unroll
        for (int i = 0; i < 8; ++i) {
            const int t = kg*8 + i - lm;
            const int bp = __builtin_amdgcn_ds_bpermute(t * 4, gi);
            hv[i] = ((unsigned)t < 11u) ? __int_as_float(bp) : 0.f;
        }
#pragma unroll
        for (int j = 0; j < 4; ++j)
            wu.p[j] = __builtin_amdgcn_cvt_pkrtz(hv[2*j], hv[2*j+1]);
    }

    // ---- per-wave barrier-free staging: wave w owns staged cols [32w, 32w+32) ----
    {
        const int cl    = lane & 31;
        const int half  = lane >> 5;
        const int ci    = w*32 + cl;
        const int gc    = x0 - 5 + ci;
        const bool okc  = (gc >= 0) && (gc < IMG);
        const int gcc   = okc ? gc : 0;
        const int slot0 = half * 24;

        union { fp16x2 p2v[12]; f16x8 v[3]; } ua, ub;
#pragma unroll
        for (int pp = 0; pp < 12; ++pp) {
            const int s0 = slot0 + 2*pp;
            const int ar0 = y0 - 5 + s0;
            const int ar1 = ar0 + 1;
            const bool ok0 = okc & (s0   < 42) & (ar0 >= 0) & (ar0 < IMG);
            const bool ok1 = okc & (s0+1 < 42) & (ar1 >= 0) & (ar1 < IMG);
            const int i0 = ok0 ? ar0 : 0, i1 = ok1 ? ar1 : 0;
            float a0 = p1[i0*IMG + gcc], a1 = p1[i1*IMG + gcc];
            float b0 = p2[i0*IMG + gcc], b1 = p2[i1*IMG + gcc];
            a0 = ok0 ? a0 : 0.f;  a1 = ok1 ? a1 : 0.f;
            b0 = ok0 ? b0 : 0.f;  b1 = ok1 ? b1 : 0.f;
            ua.p2v[pp] = __builtin_amdgcn_cvt_pkrtz(a0, a1);
            ub.p2v[pp] = __builtin_amdgcn_cvt_pkrtz(b0, b1);
        }
        _Float16* dst = &smem[ci*INSTR + slot0];
#pragma unroll
        for (int m = 0; m < 3; ++m) {
            *(f16x8*)(dst + 8*m)        = ua.v[m];
            *(f16x8*)(dst + IOFF + 8*m) = ub.v[m];
        }
    }

    const f32x4 zc = {0.f, 0.f, 0.f, 0.f};

    // ---- V-compute, BOTH strips, wave-local (no barrier after staging) ----
    f16x4 pk[2][2][5];
#pragma unroll
    for (int s = 0; s < 2; ++s) {
#pragma unroll
        for (int q = 0; q < 2; ++q) {
            const int cb = 2*w + q;
            const _Float16* colp = &smem[(cb*16 + lm)*INSTR + s*16 + kg*8];
            const f16x8 xf = *(const f16x8*)colp;
            const f16x8 yf = *(const f16x8*)(colp + IOFF);
            const f16x8 fr[5] = { xf, yf, xf*xf, yf*yf, xf*yf };
#pragma unroll
            for (int f = 0; f < 5; ++f) {
                const f32x4 dd = __builtin_amdgcn_mfma_f32_16x16x32_f16(fr[f], wu.v, zc, 0, 0, 0);
                union { fp16x2 p[2]; f16x4 v4; } c;
                c.p[0] = __builtin_amdgcn_cvt_pkrtz(dd[0], dd[1]);
                c.p[1] = __builtin_amdgcn_cvt_pkrtz(dd[2], dd[3]);
                pk[s][q][f] = c.v4;
            }
        }
    }

    __syncthreads();   // barA: ALL input reads done -> aliased buf may be written

    // ---- V0 -> buf (aliased over dead input) ----
    {
        _Float16* b = &smem[lm*VSTR + 2*w*16 + kg*4];
#pragma unroll
        for (int q = 0; q < 2; ++q)
#pragma unroll
            for (int f = 0; f < 5; ++f)
                *(f16x4*)(b + f*VOFF + q*16) = pk[0][q][f];
    }
    __syncthreads();   // barB: buf = strip-0 V

    float local = 0.f;
    // H: A = V rows (b128, k=cols contiguous), B = weights; + SSIM map.
    auto stage_h = [&]() {
#pragma unroll
        for (int q = 0; q < 2; ++q) {
            const int xx = 2*w + q;
            const _Float16* vp = &smem[lm*VSTR + xx*16 + kg*8];
            f32x4 dd[5];
#pragma unroll
            for (int f = 0; f < 5; ++f) {
                const f16x8 a = *(const f16x8*)(vp + f*VOFF);
                dd[f] = __builtin_amdgcn_mfma_f32_16x16x32_f16(a, wu.v, zc, 0, 0, 0);
            }
            const int X = xx*16 + lm;
            const bool valid = (X < OUTC) & (x0 + X < IMG);
            float s4 = 0.f;
#pragma unroll
            for (int j = 0; j < 4; ++j) {
                const float mu1 = dd[0][j], mu2 = dd[1][j];
                const float m11 = mu1*mu1, m22 = mu2*mu2, m12 = mu1*mu2;
                const float s1 = dd[2][j] - m11, s2 = dd[3][j] - m22, sx = dd[4][j] - m12;
                const float num = (2.f*m12 + 1e-4f) * (2.f*sx + 9e-4f);
                const float den = (m11 + m22 + 1e-4f) * (s1 + s2 + 9e-4f);
                s4 += num * __builtin_amdgcn_rcpf(den);
            }
            local += valid ? s4 : 0.f;
        }
    };

    stage_h();         // H0
    __syncthreads();   // barC: H0 done reading buf

    // ---- V1 -> buf ----
    {
        _Float16* b = &smem[lm*VSTR + 2*w*16 + kg*4];
#pragma unroll
        for (int q = 0; q < 2; ++q)
#pragma unroll
            for (int f = 0; f < 5; ++f)
                *(f16x4*)(b + f*VOFF + q*16) = pk[1][q][f];
    }
    __syncthreads();   // barD: buf = strip-1 V

    stage_h();         // H1

    // ---- block reduction ----
#pragma unroll
    for (int off = 32; off > 0; off >>= 1)
        local += __shfl_down(local, off, 64);
    if (lane == 0) red[w] = local;
    __syncthreads();
    if (tid == 0) {
        partials[(size_t)wid] = red[0] + red[1] + red[2] + red[3];
    }
}

__global__ __launch_bounds__(640) void ssim_finalize(const float* __restrict__ partials,
                                                     float* __restrict__ out) {
    __shared__ double red[10];
    // 2560 partials = 640 float4: exactly one vector load per thread
    const float4 v = reinterpret_cast<const float4*>(partials)[threadIdx.x];
    double s = (double)v.x + (double)v.y + (double)v.z + (double)v.w;
#pragma unroll
    for (int off = 32; off > 0; off >>= 1)
        s += __shfl_down(s, off, 64);
    if ((threadIdx.x & 63) == 0) red[threadIdx.x >> 6] = s;
    __syncthreads();
    if (threadIdx.x == 0) {
        double tot = 0.0;
#pragma unroll
        for (int i = 0; i < 10; ++i) tot += red[i];
        out[0] = (float)(1.0 - tot / (32.0 * 512.0 * 512.0));
    }
}

extern "C" void kernel_launch(void* const* d_in, const int* in_sizes, int n_in,
                              void* d_out, int out_size, void* d_ws, size_t ws_size,
                              hipStream_t stream) {
    const float* img1 = (const float*)d_in[0];
    const float* img2 = (const float*)d_in[1];
    float* out = (float*)d_out;
    float* partials = (float*)d_ws;

    dim3 grid(GX, GY, NB);   // 5 x 16 x 32 = 2560 blocks
    ssim_mfma<<<grid, 256, 0, stream>>>(img1, img2, partials);
    ssim_finalize<<<1, 640, 0, stream>>>(partials, out);
}